// Round 1
// baseline (2374.598 us; speedup 1.0000x reference)
//
#include <hip/hip_runtime.h>

#define NN 100000
#define NE 1600000

// ---------------- degree histogram ----------------
__global__ __launch_bounds__(256) void deg_kernel(const int* __restrict__ dst,
                                                  float* __restrict__ deg, int E) {
    int e = blockIdx.x * 256 + threadIdx.x;
    if (e < E) unsafeAtomicAdd(&deg[dst[e]], 1.0f);
}

// ---------------- feature scatter-add: one thread per (edge, feature) ----------------
template <int K>
__global__ __launch_bounds__(256) void scatter_kernel(const int* __restrict__ src,
                                                      const int* __restrict__ dst,
                                                      const float* __restrict__ feat,
                                                      float* __restrict__ agg, int E) {
    int tid = blockIdx.x * 256 + threadIdx.x;
    int e = tid / K;
    int k = tid - e * K;
    if (e < E) {
        int s = src[e];
        int d = dst[e];
        unsafeAtomicAdd(&agg[d * K + k], feat[s * K + k]);
    }
}

// ---------------- fused mean + dual-linear (+bias, optional relu) ----------------
// out[i,j] = (aggsum[i,:]/max(deg[i],1)) . Wl[j,:] + x[i,:] . Wr[j,:] + bias[j]
// x/out intentionally NOT __restrict__: layer 2 runs in-place on d_out (each
// thread reads its full row into registers before any store).
template <int K, int OUT, bool RELU>
__global__ __launch_bounds__(256) void linear_kernel(const float* __restrict__ aggsum,
                                                     const float* __restrict__ deg,
                                                     const float* x,
                                                     const float* __restrict__ Wl,
                                                     const float* __restrict__ Wr,
                                                     const float* __restrict__ bias,
                                                     float* out) {
    int i = blockIdx.x * 256 + threadIdx.x;
    if (i >= NN) return;
    float inv = 1.0f / fmaxf(deg[i], 1.0f);

    float4 a[K / 4], xr[K / 4];
    const float4* ap = (const float4*)(aggsum + i * K);
    const float4* xp = (const float4*)(x + i * K);
#pragma unroll
    for (int t = 0; t < K / 4; t++) {
        a[t] = ap[t];
        xr[t] = xp[t];
        a[t].x *= inv; a[t].y *= inv; a[t].z *= inv; a[t].w *= inv;
    }

    for (int j = 0; j < OUT; j += 4) {
        float4 o;
#pragma unroll
        for (int jj = 0; jj < 4; jj++) {
            const float4* wl = (const float4*)(Wl + (j + jj) * K);  // uniform -> s_load
            const float4* wr = (const float4*)(Wr + (j + jj) * K);
            float accl = 0.0f, accr = 0.0f;
#pragma unroll
            for (int t = 0; t < K / 4; t++) {
                float4 wlv = wl[t];
                float4 wrv = wr[t];
                accl += a[t].x * wlv.x + a[t].y * wlv.y + a[t].z * wlv.z + a[t].w * wlv.w;
                accr += xr[t].x * wrv.x + xr[t].y * wrv.y + xr[t].z * wrv.z + xr[t].w * wrv.w;
            }
            float acc = bias[j + jj] + accl + accr;
            (&o.x)[jj] = RELU ? fmaxf(acc, 0.0f) : acc;
        }
        *(float4*)(out + i * OUT + j) = o;
    }
}

extern "C" void kernel_launch(void* const* d_in, const int* in_sizes, int n_in,
                              void* d_out, int out_size, void* d_ws, size_t ws_size,
                              hipStream_t stream) {
    const float* x   = (const float*)d_in[0];
    const int*   ei  = (const int*)d_in[1];
    const float* W1l = (const float*)d_in[2];
    const float* W1r = (const float*)d_in[3];
    const float* b1  = (const float*)d_in[4];
    const float* W2l = (const float*)d_in[5];
    const float* W2r = (const float*)d_in[6];
    const float* b2  = (const float*)d_in[7];
    float* out = (float*)d_out;

    const int* src = ei;        // edge_index[0]
    const int* dst = ei + NE;   // edge_index[1]

    char*  ws  = (char*)d_ws;
    float* deg = (float*)ws;                    // NN floats (400 KB)
    float* agg = (float*)(ws + 401408);         // NN*128 floats (51.2 MB), layer1 uses NN*64

    // zero deg + agg
    hipMemsetAsync(d_ws, 0, 401408 + (size_t)NN * 128 * 4, stream);

    // degree (shared by both layers)
    deg_kernel<<<(NE + 255) / 256, 256, 0, stream>>>(dst, deg, NE);

    // ---- layer 1 ----
    scatter_kernel<64><<<(NE / 256) * 64, 256, 0, stream>>>(src, dst, x, agg, NE);
    linear_kernel<64, 128, true><<<(NN + 255) / 256, 256, 0, stream>>>(
        agg, deg, x, W1l, W1r, b1, out);  // h lives in d_out

    // ---- layer 2 ----
    hipMemsetAsync(agg, 0, (size_t)NN * 128 * 4, stream);
    scatter_kernel<128><<<(NE / 256) * 128, 256, 0, stream>>>(src, dst, out, agg, NE);
    linear_kernel<128, 128, false><<<(NN + 255) / 256, 256, 0, stream>>>(
        agg, deg, out, W2l, W2r, b2, out);  // in-place: row read fully before store
}

// Round 2
// 2117.360 us; speedup vs baseline: 1.1215x; 1.1215x over previous
//
#include <hip/hip_runtime.h>

#define NN 100000
#define NE 1600000

// ---------------- degree histogram ----------------
__global__ __launch_bounds__(256) void deg_kernel(const int* __restrict__ dst,
                                                  float* __restrict__ deg, int E) {
    int e = blockIdx.x * 256 + threadIdx.x;
    if (e < E) unsafeAtomicAdd(&deg[dst[e]], 1.0f);
}

// ---------------- feature scatter-add: one thread per (edge, feature) ----------------
template <int K>
__global__ __launch_bounds__(256) void scatter_kernel(const int* __restrict__ src,
                                                      const int* __restrict__ dst,
                                                      const float* __restrict__ feat,
                                                      float* __restrict__ agg, int E) {
    int tid = blockIdx.x * 256 + threadIdx.x;
    int e = tid / K;
    int k = tid - e * K;
    if (e < E) {
        int s = src[e];
        int d = dst[e];
        unsafeAtomicAdd(&agg[d * K + k], feat[s * K + k]);
    }
}

// ---------------- one matmul pass over node rows ----------------
// ACCUM=false: out[i,:] = row[i,:] @ W.T + bias
// ACCUM=true : out[i,:] += row[i,:] @ W.T   (bias unused)
// MEAN=true  : row is scaled by 1/max(deg[i],1) after load
// RELU applied at the end if set.
// rowsrc/out deliberately NOT __restrict__ (layer-2 pass A runs in-place on
// d_out: full row is loaded to registers before any store; missing restrict
// forces the compiler to keep that order).
template <int K, bool ACCUM, bool RELU, bool MEAN>
__global__ __launch_bounds__(256) void rowpass_kernel(const float* rowsrc,
                                                      const float* __restrict__ deg,
                                                      const float* __restrict__ W,
                                                      const float* __restrict__ bias,
                                                      float* out) {
    int i = blockIdx.x * 256 + threadIdx.x;
    if (i >= NN) return;

    float4 r[K / 4];
    const float4* rp = (const float4*)(rowsrc + (size_t)i * K);
#pragma unroll
    for (int t = 0; t < K / 4; t++) r[t] = rp[t];

    if (MEAN) {
        float inv = 1.0f / fmaxf(deg[i], 1.0f);
#pragma unroll
        for (int t = 0; t < K / 4; t++) {
            r[t].x *= inv; r[t].y *= inv; r[t].z *= inv; r[t].w *= inv;
        }
    }

    float* op = out + (size_t)i * 128;
    for (int j = 0; j < 128; j += 4) {
        float4 o = ACCUM ? *(const float4*)(op + j)
                         : *(const float4*)(bias + j);
#pragma unroll
        for (int jj = 0; jj < 4; jj++) {
            const float4* w = (const float4*)(W + (size_t)(j + jj) * K);  // uniform -> s_load
            float acc = 0.0f;
#pragma unroll
            for (int t = 0; t < K / 4; t++) {
                float4 wv = w[t];
                acc += r[t].x * wv.x + r[t].y * wv.y + r[t].z * wv.z + r[t].w * wv.w;
            }
            float v = (&o.x)[jj] + acc;
            (&o.x)[jj] = RELU ? fmaxf(v, 0.0f) : v;
        }
        *(float4*)(op + j) = o;
    }
}

extern "C" void kernel_launch(void* const* d_in, const int* in_sizes, int n_in,
                              void* d_out, int out_size, void* d_ws, size_t ws_size,
                              hipStream_t stream) {
    const float* x   = (const float*)d_in[0];
    const int*   ei  = (const int*)d_in[1];
    const float* W1l = (const float*)d_in[2];
    const float* W1r = (const float*)d_in[3];
    const float* b1  = (const float*)d_in[4];
    const float* W2l = (const float*)d_in[5];
    const float* W2r = (const float*)d_in[6];
    const float* b2  = (const float*)d_in[7];
    float* out = (float*)d_out;

    const int* src = ei;        // edge_index[0]
    const int* dst = ei + NE;   // edge_index[1]

    char*  ws  = (char*)d_ws;
    float* deg = (float*)ws;                    // NN floats (400 KB)
    float* agg = (float*)(ws + 401408);         // NN*128 floats (51.2 MB); layer1 uses NN*64

    const int NB = (NN + 255) / 256;

    // zero deg + agg (layer-1 portion)
    hipMemsetAsync(d_ws, 0, 401408 + (size_t)NN * 64 * 4, stream);

    // degree (shared by both layers)
    deg_kernel<<<(NE + 255) / 256, 256, 0, stream>>>(dst, deg, NE);

    // ---- layer 1 ----
    scatter_kernel<64><<<(NE / 256) * 64, 256, 0, stream>>>(src, dst, x, agg, NE);
    // out = x @ W1r.T + b1
    rowpass_kernel<64, false, false, false><<<NB, 256, 0, stream>>>(x, deg, W1r, b1, out);
    // out = relu(out + mean(agg) @ W1l.T)
    rowpass_kernel<64, true, true, true><<<NB, 256, 0, stream>>>(agg, deg, W1l, b1, out);

    // ---- layer 2 ----
    hipMemsetAsync(agg, 0, (size_t)NN * 128 * 4, stream);
    scatter_kernel<128><<<(NE / 256) * 128, 256, 0, stream>>>(src, dst, out, agg, NE);
    // out = h @ W2r.T + b2   (in-place: full row in regs before store)
    rowpass_kernel<128, false, false, false><<<NB, 256, 0, stream>>>(out, deg, W2r, b2, out);
    // out += mean(agg) @ W2l.T
    rowpass_kernel<128, true, false, true><<<NB, 256, 0, stream>>>(agg, deg, W2l, b2, out);
}

// Round 3
// 1352.142 us; speedup vs baseline: 1.7562x; 1.5659x over previous
//
#include <hip/hip_runtime.h>

#define NN 100000
#define NE 1600000
#define SCAN_BLK 2048
#define NSB ((NN + SCAN_BLK - 1) / SCAN_BLK)   // 49 blocks

// ---------------- int degree histogram ----------------
__global__ __launch_bounds__(256) void hist_kernel(const int* __restrict__ dst,
                                                   int* __restrict__ hist) {
    int e = blockIdx.x * 256 + threadIdx.x;
    if (e < NE) atomicAdd(&hist[dst[e]], 1);
}

// ---------------- exclusive scan, stage 1: per-block ----------------
__global__ __launch_bounds__(256) void scan1_kernel(int* __restrict__ data,
                                                    int* __restrict__ bsums) {
    __shared__ int s[256];
    int bid = blockIdx.x, tid = threadIdx.x;
    int base = bid * SCAN_BLK + tid * 8;
    int v[8];
    int sum = 0;
#pragma unroll
    for (int t = 0; t < 8; t++) {
        int idx = base + t;
        v[t] = (idx < NN) ? data[idx] : 0;
        sum += v[t];
    }
    s[tid] = sum;
    __syncthreads();
    for (int off = 1; off < 256; off <<= 1) {           // Hillis-Steele inclusive
        int val = (tid >= off) ? s[tid - off] : 0;
        __syncthreads();
        s[tid] += val;
        __syncthreads();
    }
    int excl = s[tid] - sum;
    if (tid == 255) bsums[bid] = s[255];
    int run = excl;
#pragma unroll
    for (int t = 0; t < 8; t++) {
        int idx = base + t;
        if (idx < NN) data[idx] = run;
        run += v[t];
    }
}

// ---------------- scan stage 2: single wave scans block sums ----------------
__global__ __launch_bounds__(64) void scan2_kernel(int* __restrict__ bsums) {
    int tid = threadIdx.x;
    int orig = (tid < NSB) ? bsums[tid] : 0;
    int v = orig;
    for (int off = 1; off < 64; off <<= 1) {
        int n = __shfl_up(v, off, 64);
        if (tid >= off) v += n;
    }
    if (tid < NSB) bsums[tid] = v - orig;               // exclusive
}

// ---------------- scan stage 3: add block offsets; init cursor ----------------
__global__ __launch_bounds__(256) void scan3_kernel(int* __restrict__ rowptr,
                                                    const int* __restrict__ bsums,
                                                    int* __restrict__ cursor) {
    int i = blockIdx.x * 256 + threadIdx.x;
    if (i < NN) {
        int v = rowptr[i] + bsums[i / SCAN_BLK];
        rowptr[i] = v;
        cursor[i] = v;
    }
    if (i == 0) rowptr[NN] = NE;
}

// ---------------- fill: scatter edge sources into CSR order ----------------
__global__ __launch_bounds__(256) void fill_kernel(const int* __restrict__ src,
                                                   const int* __restrict__ dst,
                                                   int* __restrict__ cursor,
                                                   int* __restrict__ esrc) {
    int e = blockIdx.x * 256 + threadIdx.x;
    if (e < NE) {
        int p = atomicAdd(&cursor[dst[e]], 1);
        esrc[p] = src[e];
    }
}

// ---------------- gather-aggregate: one wave per node, mean fused ----------------
template <int K>
__global__ __launch_bounds__(256) void aggregate_kernel(const float* __restrict__ feat,
                                                        const int* __restrict__ rowptr,
                                                        const int* __restrict__ esrc,
                                                        float* __restrict__ agg) {
    int node = blockIdx.x * 4 + (threadIdx.x >> 6);
    int lane = threadIdx.x & 63;
    if (node >= NN) return;
    int beg = rowptr[node], end = rowptr[node + 1];

    float acc0 = 0.0f, acc1 = 0.0f;
    int e = beg;
    for (; e + 3 < end; e += 4) {                       // 4 edges in flight
        int s0 = esrc[e], s1 = esrc[e + 1], s2 = esrc[e + 2], s3 = esrc[e + 3];
        acc0 += feat[s0 * K + lane];
        acc0 += feat[s1 * K + lane];
        acc0 += feat[s2 * K + lane];
        acc0 += feat[s3 * K + lane];
        if (K == 128) {
            acc1 += feat[s0 * K + 64 + lane];
            acc1 += feat[s1 * K + 64 + lane];
            acc1 += feat[s2 * K + 64 + lane];
            acc1 += feat[s3 * K + 64 + lane];
        }
    }
    for (; e < end; e++) {
        int s = esrc[e];
        acc0 += feat[s * K + lane];
        if (K == 128) acc1 += feat[s * K + 64 + lane];
    }
    float inv = 1.0f / fmaxf((float)(end - beg), 1.0f);
    agg[node * K + lane] = acc0 * inv;
    if (K == 128) agg[node * K + 64 + lane] = acc1 * inv;
}

// ---------------- one matmul pass over node rows ----------------
// ACCUM=false: out[i,:] = row[i,:] @ W.T + bias
// ACCUM=true : out[i,:] += row[i,:] @ W.T
// rowsrc/out deliberately NOT __restrict__ (layer-2 pass A is in-place on d_out).
template <int K, bool ACCUM, bool RELU>
__global__ __launch_bounds__(256) void rowpass_kernel(const float* rowsrc,
                                                      const float* __restrict__ W,
                                                      const float* __restrict__ bias,
                                                      float* out) {
    int i = blockIdx.x * 256 + threadIdx.x;
    if (i >= NN) return;

    float4 r[K / 4];
    const float4* rp = (const float4*)(rowsrc + (size_t)i * K);
#pragma unroll
    for (int t = 0; t < K / 4; t++) r[t] = rp[t];

    float* op = out + (size_t)i * 128;
    for (int j = 0; j < 128; j += 4) {
        float4 o = ACCUM ? *(const float4*)(op + j)
                         : *(const float4*)(bias + j);
#pragma unroll
        for (int jj = 0; jj < 4; jj++) {
            const float4* w = (const float4*)(W + (size_t)(j + jj) * K);  // uniform -> s_load
            float acc = 0.0f;
#pragma unroll
            for (int t = 0; t < K / 4; t++) {
                float4 wv = w[t];
                acc += r[t].x * wv.x + r[t].y * wv.y + r[t].z * wv.z + r[t].w * wv.w;
            }
            float v = (&o.x)[jj] + acc;
            (&o.x)[jj] = RELU ? fmaxf(v, 0.0f) : v;
        }
        *(float4*)(op + j) = o;
    }
}

extern "C" void kernel_launch(void* const* d_in, const int* in_sizes, int n_in,
                              void* d_out, int out_size, void* d_ws, size_t ws_size,
                              hipStream_t stream) {
    const float* x   = (const float*)d_in[0];
    const int*   ei  = (const int*)d_in[1];
    const float* W1l = (const float*)d_in[2];
    const float* W1r = (const float*)d_in[3];
    const float* b1  = (const float*)d_in[4];
    const float* W2l = (const float*)d_in[5];
    const float* W2r = (const float*)d_in[6];
    const float* b2  = (const float*)d_in[7];
    float* out = (float*)d_out;

    const int* src = ei;        // edge_index[0]
    const int* dst = ei + NE;   // edge_index[1]

    // workspace layout
    char* ws = (char*)d_ws;
    int*   rowptr = (int*)ws;                        // (NN+1) ints      [0, 401408)
    int*   esrc   = (int*)(ws + 401408);             // NE ints          [401408, 6801408)
    float* agg    = (float*)(ws + 6803456);          // NN*128 floats    [6803456, +51.2MB)
    // transient (only live before aggregates touch agg): alias the agg region
    int* cursor = (int*)agg;                         // NN ints
    int* bsums  = (int*)(ws + 6803456 + 409600);     // NSB ints

    const int NB = (NN + 255) / 256;

    // ---- build CSR (sorted-by-dst edge list), shared by both layers ----
    hipMemsetAsync(rowptr, 0, 401408, stream);
    hist_kernel<<<(NE + 255) / 256, 256, 0, stream>>>(dst, rowptr);
    scan1_kernel<<<NSB, 256, 0, stream>>>(rowptr, bsums);
    scan2_kernel<<<1, 64, 0, stream>>>(bsums);
    scan3_kernel<<<NB, 256, 0, stream>>>(rowptr, bsums, cursor);
    fill_kernel<<<(NE + 255) / 256, 256, 0, stream>>>(src, dst, cursor, esrc);

    // ---- layer 1 ----
    aggregate_kernel<64><<<NN / 4, 256, 0, stream>>>(x, rowptr, esrc, agg);
    rowpass_kernel<64, false, false><<<NB, 256, 0, stream>>>(x, W1r, b1, out);
    rowpass_kernel<64, true, true><<<NB, 256, 0, stream>>>(agg, W1l, b1, out);

    // ---- layer 2 ----
    aggregate_kernel<128><<<NN / 4, 256, 0, stream>>>(out, rowptr, esrc, agg);  // h = out
    rowpass_kernel<128, false, false><<<NB, 256, 0, stream>>>(out, W2r, b2, out);  // in-place
    rowpass_kernel<128, true, false><<<NB, 256, 0, stream>>>(agg, W2l, b2, out);
}

// Round 4
// 596.367 us; speedup vs baseline: 3.9818x; 2.2673x over previous
//
#include <hip/hip_runtime.h>

#define NN 100000
#define NE 1600000
#define SCAN_BLK 2048
#define NSB ((NN + SCAN_BLK - 1) / SCAN_BLK)   // 49 blocks

// ---------------- int degree histogram ----------------
__global__ __launch_bounds__(256) void hist_kernel(const int* __restrict__ dst,
                                                   int* __restrict__ hist) {
    int e = blockIdx.x * 256 + threadIdx.x;
    if (e < NE) atomicAdd(&hist[dst[e]], 1);
}

// ---------------- exclusive scan, stage 1: per-block ----------------
__global__ __launch_bounds__(256) void scan1_kernel(int* __restrict__ data,
                                                    int* __restrict__ bsums) {
    __shared__ int s[256];
    int bid = blockIdx.x, tid = threadIdx.x;
    int base = bid * SCAN_BLK + tid * 8;
    int v[8];
    int sum = 0;
#pragma unroll
    for (int t = 0; t < 8; t++) {
        int idx = base + t;
        v[t] = (idx < NN) ? data[idx] : 0;
        sum += v[t];
    }
    s[tid] = sum;
    __syncthreads();
    for (int off = 1; off < 256; off <<= 1) {           // Hillis-Steele inclusive
        int val = (tid >= off) ? s[tid - off] : 0;
        __syncthreads();
        s[tid] += val;
        __syncthreads();
    }
    int excl = s[tid] - sum;
    if (tid == 255) bsums[bid] = s[255];
    int run = excl;
#pragma unroll
    for (int t = 0; t < 8; t++) {
        int idx = base + t;
        if (idx < NN) data[idx] = run;
        run += v[t];
    }
}

// ---------------- scan stage 2: single wave scans block sums ----------------
__global__ __launch_bounds__(64) void scan2_kernel(int* __restrict__ bsums) {
    int tid = threadIdx.x;
    int orig = (tid < NSB) ? bsums[tid] : 0;
    int v = orig;
    for (int off = 1; off < 64; off <<= 1) {
        int n = __shfl_up(v, off, 64);
        if (tid >= off) v += n;
    }
    if (tid < NSB) bsums[tid] = v - orig;               // exclusive
}

// ---------------- scan stage 3: add block offsets; init cursor ----------------
__global__ __launch_bounds__(256) void scan3_kernel(int* __restrict__ rowptr,
                                                    const int* __restrict__ bsums,
                                                    int* __restrict__ cursor) {
    int i = blockIdx.x * 256 + threadIdx.x;
    if (i < NN) {
        int v = rowptr[i] + bsums[i / SCAN_BLK];
        rowptr[i] = v;
        cursor[i] = v;
    }
    if (i == 0) rowptr[NN] = NE;
}

// ---------------- fill: scatter edge sources into CSR order ----------------
__global__ __launch_bounds__(256) void fill_kernel(const int* __restrict__ src,
                                                   const int* __restrict__ dst,
                                                   int* __restrict__ cursor,
                                                   int* __restrict__ esrc) {
    int e = blockIdx.x * 256 + threadIdx.x;
    if (e < NE) {
        int p = atomicAdd(&cursor[dst[e]], 1);
        esrc[p] = src[e];
    }
}

// ---------------- gather-aggregate: one wave per node, mean fused ----------------
template <int K>
__global__ __launch_bounds__(256) void aggregate_kernel(const float* __restrict__ feat,
                                                        const int* __restrict__ rowptr,
                                                        const int* __restrict__ esrc,
                                                        float* __restrict__ agg) {
    int node = blockIdx.x * 4 + (threadIdx.x >> 6);
    int lane = threadIdx.x & 63;
    if (node >= NN) return;
    int beg = rowptr[node], end = rowptr[node + 1];

    float acc0 = 0.0f, acc1 = 0.0f;
    int e = beg;
    for (; e + 3 < end; e += 4) {                       // 4 edges in flight
        int s0 = esrc[e], s1 = esrc[e + 1], s2 = esrc[e + 2], s3 = esrc[e + 3];
        acc0 += feat[s0 * K + lane];
        acc0 += feat[s1 * K + lane];
        acc0 += feat[s2 * K + lane];
        acc0 += feat[s3 * K + lane];
        if (K == 128) {
            acc1 += feat[s0 * K + 64 + lane];
            acc1 += feat[s1 * K + 64 + lane];
            acc1 += feat[s2 * K + 64 + lane];
            acc1 += feat[s3 * K + 64 + lane];
        }
    }
    for (; e < end; e++) {
        int s = esrc[e];
        acc0 += feat[s * K + lane];
        if (K == 128) acc1 += feat[s * K + 64 + lane];
    }
    float inv = 1.0f / fmaxf((float)(end - beg), 1.0f);
    agg[node * K + lane] = acc0 * inv;
    if (K == 128) agg[node * K + 64 + lane] = acc1 * inv;
}

// ---------------- fused dual-input tiled GEMM ----------------
// out[n, 0:128] = A1[n,0:KA] @ Wa.T + A2[n,0:KB] @ Wb.T + bias   (+ReLU)
// Block tile: 128 nodes x 128 outputs. 256 threads, 8x8 micro-tile each,
// split 4+4 (rows ni*4..+3 and 64+ni*4..+3) so LDS reads alias at most
// 2-way (free per m136). A/W chunks (32xK) staged transposed in LDS.
// A2/out deliberately NOT __restrict__: layer 2 is in-place on d_out (each
// block reads only its own 128 rows; stores happen only in the epilogue).
template <int KA, int KB, bool RELU>
__global__ __launch_bounds__(256, 4) void gemm_kernel(const float* __restrict__ A1,
                                                      const float* A2,
                                                      const float* __restrict__ Wa,
                                                      const float* __restrict__ Wb,
                                                      const float* __restrict__ bias,
                                                      float* out) {
    __shared__ float As[32][128];
    __shared__ float Bs[32][128];

    const int t = threadIdx.x;
    const int base = blockIdx.x * 128;
    const int half = t & 1;        // which 16-k half this thread stages
    const int srow = t >> 1;       // staging row: node-in-tile / output j
    const int ni = t & 15;
    const int ji = t >> 4;

    float acc[8][8];
#pragma unroll
    for (int i = 0; i < 8; i++)
#pragma unroll
        for (int j = 0; j < 8; j++) acc[i][j] = 0.0f;

    const int NCH = (KA + KB) / 32;
#pragma unroll
    for (int c = 0; c < NCH; ++c) {
        const bool inA = (c * 32) < KA;
        const float* Ap = inA ? A1 : A2;
        const float* Wp = inA ? Wa : Wb;
        const int K  = inA ? KA : KB;
        const int kb = inA ? c * 32 : c * 32 - KA;

        __syncthreads();
        {
            int gn = base + srow;
            if (gn > NN - 1) gn = NN - 1;               // clamp: tail rows discarded later
            const float* ar = Ap + (size_t)gn * K + kb + half * 16;
            const float* wr = Wp + (size_t)srow * K + kb + half * 16;
#pragma unroll
            for (int u = 0; u < 4; ++u) {
                float4 av = *(const float4*)(ar + u * 4);
                float4 wv = *(const float4*)(wr + u * 4);
                int k0 = half * 16 + u * 4;
                As[k0 + 0][srow] = av.x; As[k0 + 1][srow] = av.y;
                As[k0 + 2][srow] = av.z; As[k0 + 3][srow] = av.w;
                Bs[k0 + 0][srow] = wv.x; Bs[k0 + 1][srow] = wv.y;
                Bs[k0 + 2][srow] = wv.z; Bs[k0 + 3][srow] = wv.w;
            }
        }
        __syncthreads();

#pragma unroll 4
        for (int k = 0; k < 32; ++k) {
            float4 a0 = *(const float4*)&As[k][ni * 4];
            float4 a1 = *(const float4*)&As[k][64 + ni * 4];
            float4 b0 = *(const float4*)&Bs[k][ji * 4];
            float4 b1 = *(const float4*)&Bs[k][64 + ji * 4];
            float a[8] = {a0.x, a0.y, a0.z, a0.w, a1.x, a1.y, a1.z, a1.w};
            float b[8] = {b0.x, b0.y, b0.z, b0.w, b1.x, b1.y, b1.z, b1.w};
#pragma unroll
            for (int i = 0; i < 8; ++i)
#pragma unroll
                for (int j = 0; j < 8; ++j) acc[i][j] += a[i] * b[j];
        }
    }

    float4 bz0 = *(const float4*)(bias + ji * 4);
    float4 bz1 = *(const float4*)(bias + 64 + ji * 4);
#pragma unroll
    for (int i = 0; i < 8; ++i) {
        int r = base + (i < 4 ? ni * 4 + i : 64 + ni * 4 + (i - 4));
        if (r >= NN) continue;
        float4 o0, o1;
        o0.x = acc[i][0] + bz0.x; o0.y = acc[i][1] + bz0.y;
        o0.z = acc[i][2] + bz0.z; o0.w = acc[i][3] + bz0.w;
        o1.x = acc[i][4] + bz1.x; o1.y = acc[i][5] + bz1.y;
        o1.z = acc[i][6] + bz1.z; o1.w = acc[i][7] + bz1.w;
        if (RELU) {
            o0.x = fmaxf(o0.x, 0.0f); o0.y = fmaxf(o0.y, 0.0f);
            o0.z = fmaxf(o0.z, 0.0f); o0.w = fmaxf(o0.w, 0.0f);
            o1.x = fmaxf(o1.x, 0.0f); o1.y = fmaxf(o1.y, 0.0f);
            o1.z = fmaxf(o1.z, 0.0f); o1.w = fmaxf(o1.w, 0.0f);
        }
        float* op = out + (size_t)r * 128;
        *(float4*)(op + ji * 4) = o0;
        *(float4*)(op + 64 + ji * 4) = o1;
    }
}

extern "C" void kernel_launch(void* const* d_in, const int* in_sizes, int n_in,
                              void* d_out, int out_size, void* d_ws, size_t ws_size,
                              hipStream_t stream) {
    const float* x   = (const float*)d_in[0];
    const int*   ei  = (const int*)d_in[1];
    const float* W1l = (const float*)d_in[2];
    const float* W1r = (const float*)d_in[3];
    const float* b1  = (const float*)d_in[4];
    const float* W2l = (const float*)d_in[5];
    const float* W2r = (const float*)d_in[6];
    const float* b2  = (const float*)d_in[7];
    float* out = (float*)d_out;

    const int* src = ei;        // edge_index[0]
    const int* dst = ei + NE;   // edge_index[1]

    // workspace layout
    char* ws = (char*)d_ws;
    int*   rowptr = (int*)ws;                        // (NN+1) ints      [0, 401408)
    int*   esrc   = (int*)(ws + 401408);             // NE ints          [401408, 6801408)
    float* agg    = (float*)(ws + 6803456);          // NN*128 floats    [6803456, +51.2MB)
    // transient (dead once aggregates write agg): alias the agg region
    int* cursor = (int*)agg;                         // NN ints
    int* bsums  = (int*)(ws + 6803456 + 409600);     // NSB ints

    const int NB   = (NN + 255) / 256;
    const int NBT  = (NN + 127) / 128;               // gemm tiles

    // ---- build CSR (edge list sorted by dst), shared by both layers ----
    hipMemsetAsync(rowptr, 0, 401408, stream);
    hist_kernel<<<(NE + 255) / 256, 256, 0, stream>>>(dst, rowptr);
    scan1_kernel<<<NSB, 256, 0, stream>>>(rowptr, bsums);
    scan2_kernel<<<1, 64, 0, stream>>>(bsums);
    scan3_kernel<<<NB, 256, 0, stream>>>(rowptr, bsums, cursor);
    fill_kernel<<<(NE + 255) / 256, 256, 0, stream>>>(src, dst, cursor, esrc);

    // ---- layer 1: out = relu(mean(agg) @ W1l.T + x @ W1r.T + b1) ----
    aggregate_kernel<64><<<NN / 4, 256, 0, stream>>>(x, rowptr, esrc, agg);
    gemm_kernel<64, 64, true><<<NBT, 256, 0, stream>>>(agg, x, W1l, W1r, b1, out);

    // ---- layer 2: out = mean(agg2) @ W2l.T + h @ W2r.T + b2  (h = out, in-place) ----
    aggregate_kernel<128><<<NN / 4, 256, 0, stream>>>(out, rowptr, esrc, agg);
    gemm_kernel<128, 128, false><<<NBT, 256, 0, stream>>>(agg, out, W2l, W2r, b2, out);
}